// Round 7
// baseline (322.788 us; speedup 1.0000x reference)
//
#include <hip/hip_runtime.h>

// ---------------------------------------------------------------------------
// TemporalHeteroConv on MI355X.  N=100000 nodes, E=800000 edges, C=64, H=4.
// Pipeline (r7):
//   k_hn     : lane = node. h row in registers via scalar-broadcast W;
//              writes h16 (bf16) + fused u/v attention tables.
//   k_deg    : rank[e] = atomicAdd(deg[dst]) only.
//   scan1/2  : exclusive scan of deg (bsums[i>>8] folded into consumers).
//   k_fill   : recomputes scores (u[src]+v[dst] gathers, L2-resident) and
//              scatters src + es VALUE into CSR slots. [est buffer killed]
//   k_pw     : pack Pw into bf16 MFMA B-fragment order (32 KB, L2-resident).
//   k_aggproj: FUSED k_agg+k_projm. Block=16 nodes. Phase 1: wave aggregates
//              4 nodes (pipelined groups-of-4, bf16 h gather) -> LDS rows.
//              Phase 2: wave = one 16-col MFMA slice, LN via E[z^2]-mu^2 with
//              one cross-wave LDS reduction, residual+ReLU, store.
//              [kills 51MB agg write + 51MB read + one dispatch]
// ---------------------------------------------------------------------------

typedef __attribute__((ext_vector_type(8))) short bf16x8;
typedef __attribute__((ext_vector_type(4))) float f32x4;

__device__ __forceinline__ unsigned short f2bf(float f) {
  unsigned int u = __float_as_uint(f);
  u += 0x7FFFu + ((u >> 16) & 1u);          // RNE
  return (unsigned short)(u >> 16);
}
__device__ __forceinline__ float bf2f(unsigned short s) {
  return __uint_as_float(((unsigned int)s) << 16);
}
__device__ __forceinline__ unsigned int pk(float a, float b) {
  return (unsigned int)f2bf(a) | ((unsigned int)f2bf(b) << 16);
}

#define FMA4(P, S, R) { P.x = fmaf(S, R.x, P.x); P.y = fmaf(S, R.y, P.y); \
                        P.z = fmaf(S, R.z, P.z); P.w = fmaf(S, R.w, P.w); }

// ------- h/u/v producer: lane = node, scalar-broadcast W, no LDS ----------
__global__ __launch_bounds__(64) void k_hn(const float* __restrict__ x,
    const float* __restrict__ Ww, const float* __restrict__ Wb,
    const float* __restrict__ attn_w,
    unsigned short* __restrict__ h16, float4* __restrict__ u,
    float4* __restrict__ v, int N)
{
  const int n = blockIdx.x * 64 + threadIdx.x;
  const bool valid = (n < N);
  const int nc = valid ? n : (N - 1);

  float o[64];
  #pragma unroll
  for (int c = 0; c < 64; ++c) o[c] = Wb[c];

  const float* xr = x + (size_t)nc * 64;
  for (int ch = 0; ch < 16; ++ch) {
    float4 xv = *(const float4*)(xr + ch * 4);
    float a[4] = {xv.x, xv.y, xv.z, xv.w};
    #pragma unroll
    for (int kk = 0; kk < 4; ++kk) {
      const float* Wr = Ww + (size_t)(ch * 4 + kk) * 64;
      #pragma unroll
      for (int c = 0; c < 64; ++c)
        o[c] = fmaf(a[kk], Wr[c], o[c]);
    }
  }

  float4 uu = make_float4(0.f, 0.f, 0.f, 0.f);
  float4 vv = make_float4(0.f, 0.f, 0.f, 0.f);
  const float4* aw = (const float4*)attn_w;
  #pragma unroll
  for (int c = 0; c < 64; ++c) {
    float4 r1 = aw[c];
    float4 r2 = aw[64 + c];
    FMA4(uu, o[c], r1);
    FMA4(vv, o[c], r2);
  }

  if (valid) {
    unsigned int* hr = (unsigned int*)(h16 + (size_t)n * 64);
    #pragma unroll
    for (int i = 0; i < 8; ++i) {
      uint4 w;
      w.x = pk(o[i*8+0], o[i*8+1]);
      w.y = pk(o[i*8+2], o[i*8+3]);
      w.z = pk(o[i*8+4], o[i*8+5]);
      w.w = pk(o[i*8+6], o[i*8+7]);
      *(uint4*)(hr + i * 4) = w;
    }
    u[n] = uu;
    v[n] = vv;
  }
}

// -------- degree count + slot rank ----------------------------------------
__global__ __launch_bounds__(256) void k_deg(const int* __restrict__ ei,
    int* __restrict__ deg, int* __restrict__ rank, int E)
{
  int e = blockIdx.x * 256 + threadIdx.x;
  if (e < E) rank[e] = atomicAdd(&deg[ei[E + e]], 1);
}

// ---------------- CSR offsets: block-local scan + block sums ---------------
__global__ __launch_bounds__(256) void scan1(const int* __restrict__ deg,
    int* __restrict__ offs, int* __restrict__ bsums, int N)
{
  int i = blockIdx.x * 256 + threadIdx.x;
  int lane = threadIdx.x & 63;
  int w = threadIdx.x >> 6;
  int v = (i < N) ? deg[i] : 0;
  int s = v;
  #pragma unroll
  for (int d = 1; d < 64; d <<= 1) {
    int t = __shfl_up(s, d, 64);
    if (lane >= d) s += t;
  }
  __shared__ int wsum[4];
  if (lane == 63) wsum[w] = s;
  __syncthreads();
  int add = 0;
  if (w > 0) add += wsum[0];
  if (w > 1) add += wsum[1];
  if (w > 2) add += wsum[2];
  if (i < N) offs[i] = s - v + add;                 // block-exclusive
  if (threadIdx.x == 255) bsums[blockIdx.x] = wsum[0] + wsum[1] + wsum[2] + wsum[3];
}

__global__ __launch_bounds__(512) void scan2(int* bsums, int NB)
{
  __shared__ int lds[512];
  int t = threadIdx.x;
  int v = (t < NB) ? bsums[t] : 0;
  lds[t] = v;
  __syncthreads();
  for (int s = 1; s < 512; s <<= 1) {
    int a = (t >= s) ? lds[t - s] : 0;
    __syncthreads();
    lds[t] += a;
    __syncthreads();
  }
  if (t < NB) bsums[t] = lds[t] - v;                // exclusive
}

// -------- CSR fill: compute score here, scatter src + es value -------------
__global__ __launch_bounds__(256) void k_fill(const int* __restrict__ ei,
    const float* __restrict__ et, const int* __restrict__ ctime,
    const float* __restrict__ drate, const float4* __restrict__ u,
    const float4* __restrict__ v, const float* __restrict__ attn_b,
    const int* __restrict__ offs, const int* __restrict__ bsums,
    const int* __restrict__ rank,
    int* __restrict__ csr_src, float4* __restrict__ csr_es, int E)
{
  int e = blockIdx.x * 256 + threadIdx.x;
  if (e >= E) return;
  const int s = ei[e];
  const int d = ei[E + e];
  const float4 us = u[s];
  const float4 vd = v[d];
  const float4 ab = *(const float4*)attn_b;
  const float lam = log1pf(__expf(drate[0]));
  const float w = __expf(-lam * ((float)ctime[0] - et[e]));

  float4 o; float t;
  t = us.x + vd.x + ab.x; t = (t > 0.f ? t : 0.2f * t) * w; o.x = __expf(t);
  t = us.y + vd.y + ab.y; t = (t > 0.f ? t : 0.2f * t) * w; o.y = __expf(t);
  t = us.z + vd.z + ab.z; t = (t > 0.f ? t : 0.2f * t) * w; o.z = __expf(t);
  t = us.w + vd.w + ab.w; t = (t > 0.f ? t : 0.2f * t) * w; o.w = __expf(t);

  const int pos = offs[d] + bsums[d >> 8] + rank[e];
  csr_src[pos] = s;
  csr_es[pos] = o;
}

// ------- pack Pw (256x64 fp32) into bf16 MFMA B-fragment order ------------
__global__ __launch_bounds__(256) void k_pw(const float* __restrict__ Pw,
    unsigned short* __restrict__ Bf)
{
  int i = blockIdx.x * 256 + threadIdx.x;   // 0..16383
  int j    = i & 7;
  int lane = (i >> 3) & 63;
  int cb   = (i >> 9) & 3;
  int ks   = i >> 11;
  int k    = ks * 32 + (lane >> 4) * 8 + j;
  int colg = cb * 16 + (lane & 15);
  Bf[i] = f2bf(Pw[(size_t)k * 64 + colg]);
}

// ------- fused aggregation + MFMA proj + residual/LN/ReLU ------------------
__global__ __launch_bounds__(256) void k_aggproj(
    const unsigned short* __restrict__ h16,
    const int* __restrict__ csr_src, const float4* __restrict__ csr_es,
    const int* __restrict__ offs, const int* __restrict__ bsums,
    const unsigned short* __restrict__ Bf,
    const float* __restrict__ x, const float* __restrict__ Pb,
    const float* __restrict__ lg, const float* __restrict__ lb,
    float* __restrict__ out, int N, int E)
{
  __shared__ unsigned short At[16][264];    // agg rows; 528B stride: 2-way max
  __shared__ float S1[16][4], S2[16][4];    // cross-wave LN partials

  const int lane = threadIdx.x & 63;
  const int wv = threadIdx.x >> 6;
  const int base = blockIdx.x * 16;
  const int c = lane;

  // ---- phase 1: each wave aggregates 4 node rows into LDS (bf16) ----
  for (int i = 0; i < 4; ++i) {
    const int row = wv * 4 + i;
    const int n = base + row;
    float acc0 = 0.f, acc1 = 0.f, acc2 = 0.f, acc3 = 0.f;
    float den0 = 0.f, den1 = 0.f, den2 = 0.f, den3 = 0.f;
    if (n < N) {
      const int p0 = offs[n] + bsums[n >> 8];
      const int p1 = (n + 1 < N) ? (offs[n + 1] + bsums[(n + 1) >> 8]) : E;
      const int nf = (p1 - p0) & ~3;

      int4   sA = make_int4(0, 0, 0, 0);
      float4 eA0, eA1, eA2, eA3;
      float  gA0 = 0.f, gA1 = 0.f, gA2 = 0.f, gA3 = 0.f;
      if (nf) {
        sA = *(const int4*)(csr_src + p0);          // uniform -> s_load
        eA0 = csr_es[p0];     eA1 = csr_es[p0 + 1];
        eA2 = csr_es[p0 + 2]; eA3 = csr_es[p0 + 3];
        gA0 = bf2f(h16[(size_t)sA.x * 64 + c]);
        gA1 = bf2f(h16[(size_t)sA.y * 64 + c]);
        gA2 = bf2f(h16[(size_t)sA.z * 64 + c]);
        gA3 = bf2f(h16[(size_t)sA.w * 64 + c]);
      }
      for (int p = p0; p < p0 + nf; p += 4) {
        int4 sB; float4 eB0, eB1, eB2, eB3;
        float gB0, gB1, gB2, gB3;
        const bool more = (p + 4 < p0 + nf);
        if (more) {                                 // prefetch next group
          sB = *(const int4*)(csr_src + p + 4);
          eB0 = csr_es[p + 4]; eB1 = csr_es[p + 5];
          eB2 = csr_es[p + 6]; eB3 = csr_es[p + 7];
          gB0 = bf2f(h16[(size_t)sB.x * 64 + c]);
          gB1 = bf2f(h16[(size_t)sB.y * 64 + c]);
          gB2 = bf2f(h16[(size_t)sB.z * 64 + c]);
          gB3 = bf2f(h16[(size_t)sB.w * 64 + c]);
        }
        den0 += (eA0.x + eA1.x) + (eA2.x + eA3.x);
        den1 += (eA0.y + eA1.y) + (eA2.y + eA3.y);
        den2 += (eA0.z + eA1.z) + (eA2.z + eA3.z);
        den3 += (eA0.w + eA1.w) + (eA2.w + eA3.w);
        acc0 = fmaf(eA0.x, gA0, fmaf(eA1.x, gA1, fmaf(eA2.x, gA2, fmaf(eA3.x, gA3, acc0))));
        acc1 = fmaf(eA0.y, gA0, fmaf(eA1.y, gA1, fmaf(eA2.y, gA2, fmaf(eA3.y, gA3, acc1))));
        acc2 = fmaf(eA0.z, gA0, fmaf(eA1.z, gA1, fmaf(eA2.z, gA2, fmaf(eA3.z, gA3, acc2))));
        acc3 = fmaf(eA0.w, gA0, fmaf(eA1.w, gA1, fmaf(eA2.w, gA2, fmaf(eA3.w, gA3, acc3))));
        if (more) {
          eA0 = eB0; eA1 = eB1; eA2 = eB2; eA3 = eB3;
          gA0 = gB0; gA1 = gB1; gA2 = gB2; gA3 = gB3;
        }
      }
      for (int p = p0 + nf; p < p1; ++p) {          // tail (<=3, wave-uniform)
        int s = csr_src[p];
        float4 ev = csr_es[p];
        float g = bf2f(h16[(size_t)s * 64 + c]);
        den0 += ev.x; den1 += ev.y; den2 += ev.z; den3 += ev.w;
        acc0 = fmaf(ev.x, g, acc0);
        acc1 = fmaf(ev.y, g, acc1);
        acc2 = fmaf(ev.z, g, acc2);
        acc3 = fmaf(ev.w, g, acc3);
      }
    }
    uint2 w;
    w.x = pk(acc0 / (den0 + 1e-8f), acc1 / (den1 + 1e-8f));
    w.y = pk(acc2 / (den2 + 1e-8f), acc3 / (den3 + 1e-8f));
    *(uint2*)&At[row][c * 4] = w;                   // ds_write_b64, no conflict
  }
  __syncthreads();

  // ---- phase 2: wave wv = col block wv (16 cols), 8 K-step MFMAs ----
  const int col = lane & 15, quad = lane >> 4;
  f32x4 acc = {0.f, 0.f, 0.f, 0.f};
  #pragma unroll
  for (int ks = 0; ks < 8; ++ks) {
    bf16x8 av = *(const bf16x8*)&At[lane & 15][ks * 32 + quad * 8];
    bf16x8 bv = *(const bf16x8*)(Bf + ((size_t)(ks * 4 + wv) * 64 + lane) * 8);
    acc = __builtin_amdgcn_mfma_f32_16x16x32_bf16(av, bv, acc, 0, 0, 0);
  }

  const int gcol = wv * 16 + col;
  const float pb = Pb[gcol], gg = lg[gcol], bb = lb[gcol];
  float z[4];
  #pragma unroll
  for (int r = 0; r < 4; ++r) {
    int node = base + quad * 4 + r;
    int nn = node < N ? node : N - 1;
    z[r] = acc[r] + pb + x[(size_t)nn * 64 + gcol];
    float s1 = z[r], s2 = z[r] * z[r];
    s1 += __shfl_xor(s1, 1, 64); s2 += __shfl_xor(s2, 1, 64);
    s1 += __shfl_xor(s1, 2, 64); s2 += __shfl_xor(s2, 2, 64);
    s1 += __shfl_xor(s1, 4, 64); s2 += __shfl_xor(s2, 4, 64);
    s1 += __shfl_xor(s1, 8, 64); s2 += __shfl_xor(s2, 8, 64);
    if (col == 0) { S1[quad * 4 + r][wv] = s1; S2[quad * 4 + r][wv] = s2; }
  }
  __syncthreads();

  #pragma unroll
  for (int r = 0; r < 4; ++r) {
    const int ni = quad * 4 + r;
    float sum1 = (S1[ni][0] + S1[ni][1]) + (S1[ni][2] + S1[ni][3]);
    float sum2 = (S2[ni][0] + S2[ni][1]) + (S2[ni][2] + S2[ni][3]);
    float mu = sum1 * 0.015625f;
    float var = fmaf(-mu, mu, sum2 * 0.015625f);    // E[z^2] - mu^2
    float inv = rsqrtf(var + 1e-5f);
    int node = base + ni;
    if (node < N)
      out[(size_t)node * 64 + gcol] = fmaxf(fmaf(gg * (z[r] - mu), inv, bb), 0.f);
  }
}

// ---------------------------------------------------------------------------
extern "C" void kernel_launch(void* const* d_in, const int* in_sizes, int n_in,
                              void* d_out, int out_size, void* d_ws, size_t ws_size,
                              hipStream_t stream)
{
  const float* x  = (const float*)d_in[0];
  const int*   ei = (const int*)d_in[1];
  const float* et = (const float*)d_in[2];
  const int*   ct = (const int*)d_in[3];
  const float* Ww = (const float*)d_in[4];
  const float* Wb = (const float*)d_in[5];
  const float* aw = (const float*)d_in[6];
  const float* ab = (const float*)d_in[7];
  const float* dr = (const float*)d_in[8];
  const float* Pw = (const float*)d_in[9];
  const float* Pb = (const float*)d_in[10];
  const float* lg = (const float*)d_in[11];
  const float* lb = (const float*)d_in[12];
  float* out = (float*)d_out;

  const int N = in_sizes[0] / 64;
  const int E = in_sizes[2];

  char* ws = (char*)d_ws;
  size_t off = 0;
  auto take = [&](size_t bytes) -> char* {
    char* p = ws + off;
    off = (off + bytes + 255) & ~(size_t)255;
    return p;
  };
  unsigned short* h16 = (unsigned short*)take((size_t)N * 64 * 2);
  int*    deg    = (int*)take((size_t)N * 4);
  int*    offs   = (int*)take((size_t)N * 4);
  int*    bsums  = (int*)take(512 * 4);
  int*    rank   = (int*)take((size_t)E * 4);
  int*    csr_src= (int*)take((size_t)E * 4);
  float4* csr_es = (float4*)take((size_t)E * 16);
  float4* u      = (float4*)take((size_t)N * 16);
  float4* v      = (float4*)take((size_t)N * 16);
  unsigned short* Bf = (unsigned short*)take(16384 * 2);

  hipMemsetAsync(deg, 0, (size_t)N * 4, stream);

  k_pw<<<64, 256, 0, stream>>>(Pw, Bf);
  k_hn<<<(N + 63) / 64, 64, 0, stream>>>(x, Ww, Wb, aw, h16, u, v, N);
  k_deg<<<(E + 255) / 256, 256, 0, stream>>>(ei, deg, rank, E);
  const int NB = (N + 255) / 256;
  scan1<<<NB, 256, 0, stream>>>(deg, offs, bsums, N);
  scan2<<<1, 512, 0, stream>>>(bsums, NB);
  k_fill<<<(E + 255) / 256, 256, 0, stream>>>(ei, et, ct, dr, u, v, ab,
                                              offs, bsums, rank, csr_src, csr_es, E);
  k_aggproj<<<(N + 15) / 16, 256, 0, stream>>>(h16, csr_src, csr_es, offs, bsums,
                                               Bf, x, Pb, lg, lb, out, N, E);
}

// Round 8
// 319.685 us; speedup vs baseline: 1.0097x; 1.0097x over previous
//
#include <hip/hip_runtime.h>

// ---------------------------------------------------------------------------
// TemporalHeteroConv on MI355X.  N=100000 nodes, E=800000 edges, C=64, H=4.
// Pipeline (r8 = r6 structure + streaming k_agg; r7 fusion reverted: it cost
// 800k LDS bank conflicts + phase-barrier imbalance, 111us vs 59+25 split):
//   k_hn     : lane = node. h row in registers via scalar-broadcast W;
//              writes h16 (bf16) + fused u/v attention tables.
//   k_deg    : rank[e] = atomicAdd(deg[dst]).
//   scan1/2/3: exclusive scan of deg -> final offs2[N+1].
//   k_fill   : recomputes scores from u/v (L2-resident) and scatters
//              src + es VALUE into CSR slots (no est buffer).
//   k_agg    : EDGE-BALANCED streaming segmented aggregation. 8192 waves
//              binary-search equal ~98-edge CSR slices (snapped to node
//              starts), stream edges with depth-2 group prefetch (12 gathers
//              in flight), flush accumulators at uniform node boundaries.
//   k_pw     : pack Pw into bf16 MFMA B-fragment order (32 KB, L2-resident).
//   k_projm  : MFMA proj GEMM agg(N,256)@Pw(256,64), wave per 16-node tile,
//              LN+residual+ReLU epilogue in C/D layout.
// ---------------------------------------------------------------------------

typedef __attribute__((ext_vector_type(8))) short bf16x8;
typedef __attribute__((ext_vector_type(4))) float f32x4;

__device__ __forceinline__ unsigned short f2bf(float f) {
  unsigned int u = __float_as_uint(f);
  u += 0x7FFFu + ((u >> 16) & 1u);          // RNE
  return (unsigned short)(u >> 16);
}
__device__ __forceinline__ float bf2f(unsigned short s) {
  return __uint_as_float(((unsigned int)s) << 16);
}
__device__ __forceinline__ unsigned int pk(float a, float b) {
  return (unsigned int)f2bf(a) | ((unsigned int)f2bf(b) << 16);
}

#define FMA4(P, S, R) { P.x = fmaf(S, R.x, P.x); P.y = fmaf(S, R.y, P.y); \
                        P.z = fmaf(S, R.z, P.z); P.w = fmaf(S, R.w, P.w); }

// ------- h/u/v producer: lane = node, scalar-broadcast W, no LDS ----------
__global__ __launch_bounds__(64) void k_hn(const float* __restrict__ x,
    const float* __restrict__ Ww, const float* __restrict__ Wb,
    const float* __restrict__ attn_w,
    unsigned short* __restrict__ h16, float4* __restrict__ u,
    float4* __restrict__ v, int N)
{
  const int n = blockIdx.x * 64 + threadIdx.x;
  const bool valid = (n < N);
  const int nc = valid ? n : (N - 1);

  float o[64];
  #pragma unroll
  for (int c = 0; c < 64; ++c) o[c] = Wb[c];

  const float* xr = x + (size_t)nc * 64;
  for (int ch = 0; ch < 16; ++ch) {
    float4 xv = *(const float4*)(xr + ch * 4);
    float a[4] = {xv.x, xv.y, xv.z, xv.w};
    #pragma unroll
    for (int kk = 0; kk < 4; ++kk) {
      const float* Wr = Ww + (size_t)(ch * 4 + kk) * 64;
      #pragma unroll
      for (int c = 0; c < 64; ++c)
        o[c] = fmaf(a[kk], Wr[c], o[c]);
    }
  }

  float4 uu = make_float4(0.f, 0.f, 0.f, 0.f);
  float4 vv = make_float4(0.f, 0.f, 0.f, 0.f);
  const float4* aw = (const float4*)attn_w;
  #pragma unroll
  for (int c = 0; c < 64; ++c) {
    float4 r1 = aw[c];
    float4 r2 = aw[64 + c];
    FMA4(uu, o[c], r1);
    FMA4(vv, o[c], r2);
  }

  if (valid) {
    unsigned int* hr = (unsigned int*)(h16 + (size_t)n * 64);
    #pragma unroll
    for (int i = 0; i < 8; ++i) {
      uint4 w;
      w.x = pk(o[i*8+0], o[i*8+1]);
      w.y = pk(o[i*8+2], o[i*8+3]);
      w.z = pk(o[i*8+4], o[i*8+5]);
      w.w = pk(o[i*8+6], o[i*8+7]);
      *(uint4*)(hr + i * 4) = w;
    }
    u[n] = uu;
    v[n] = vv;
  }
}

// -------- degree count + slot rank ----------------------------------------
__global__ __launch_bounds__(256) void k_deg(const int* __restrict__ ei,
    int* __restrict__ deg, int* __restrict__ rank, int E)
{
  int e = blockIdx.x * 256 + threadIdx.x;
  if (e < E) rank[e] = atomicAdd(&deg[ei[E + e]], 1);
}

// ---------------- CSR offsets ----------------------------------------------
__global__ __launch_bounds__(256) void scan1(const int* __restrict__ deg,
    int* __restrict__ offs, int* __restrict__ bsums, int N)
{
  int i = blockIdx.x * 256 + threadIdx.x;
  int lane = threadIdx.x & 63;
  int w = threadIdx.x >> 6;
  int v = (i < N) ? deg[i] : 0;
  int s = v;
  #pragma unroll
  for (int d = 1; d < 64; d <<= 1) {
    int t = __shfl_up(s, d, 64);
    if (lane >= d) s += t;
  }
  __shared__ int wsum[4];
  if (lane == 63) wsum[w] = s;
  __syncthreads();
  int add = 0;
  if (w > 0) add += wsum[0];
  if (w > 1) add += wsum[1];
  if (w > 2) add += wsum[2];
  if (i < N) offs[i] = s - v + add;                 // block-exclusive
  if (threadIdx.x == 255) bsums[blockIdx.x] = wsum[0] + wsum[1] + wsum[2] + wsum[3];
}

__global__ __launch_bounds__(512) void scan2(int* bsums, int NB)
{
  __shared__ int lds[512];
  int t = threadIdx.x;
  int v = (t < NB) ? bsums[t] : 0;
  lds[t] = v;
  __syncthreads();
  for (int s = 1; s < 512; s <<= 1) {
    int a = (t >= s) ? lds[t - s] : 0;
    __syncthreads();
    lds[t] += a;
    __syncthreads();
  }
  if (t < NB) bsums[t] = lds[t] - v;                // exclusive
}

__global__ __launch_bounds__(256) void scan3(const int* __restrict__ offs,
    const int* __restrict__ bsums, int* __restrict__ offs2, int N, int E)
{
  int i = blockIdx.x * 256 + threadIdx.x;
  if (i < N) offs2[i] = offs[i] + bsums[i >> 8];
  if (i == N) offs2[N] = E;
}

// -------- CSR fill: compute score here, scatter src + es value -------------
__global__ __launch_bounds__(256) void k_fill(const int* __restrict__ ei,
    const float* __restrict__ et, const int* __restrict__ ctime,
    const float* __restrict__ drate, const float4* __restrict__ u,
    const float4* __restrict__ v, const float* __restrict__ attn_b,
    const int* __restrict__ offs2, const int* __restrict__ rank,
    int* __restrict__ csr_src, float4* __restrict__ csr_es, int E)
{
  int e = blockIdx.x * 256 + threadIdx.x;
  if (e >= E) return;
  const int s = ei[e];
  const int d = ei[E + e];
  const float4 us = u[s];
  const float4 vd = v[d];
  const float4 ab = *(const float4*)attn_b;
  const float lam = log1pf(__expf(drate[0]));
  const float w = __expf(-lam * ((float)ctime[0] - et[e]));

  float4 o; float t;
  t = us.x + vd.x + ab.x; t = (t > 0.f ? t : 0.2f * t) * w; o.x = __expf(t);
  t = us.y + vd.y + ab.y; t = (t > 0.f ? t : 0.2f * t) * w; o.y = __expf(t);
  t = us.z + vd.z + ab.z; t = (t > 0.f ? t : 0.2f * t) * w; o.z = __expf(t);
  t = us.w + vd.w + ab.w; t = (t > 0.f ? t : 0.2f * t) * w; o.w = __expf(t);

  const int pos = offs2[d] + rank[e];
  csr_src[pos] = s;
  csr_es[pos] = o;
}

// -------- streaming segmented aggregation (edge-balanced waves) ------------
__global__ __launch_bounds__(256) void k_agg(const unsigned short* __restrict__ h16,
    const int* __restrict__ csr_src, const float4* __restrict__ csr_es,
    const int* __restrict__ offs2, unsigned short* __restrict__ agg,
    int N, int E, int W)
{
  const int c = threadIdx.x & 63;
  const int wvid = blockIdx.x * 4 + (threadIdx.x >> 6);

  const int eb = (int)((long)wvid * E / W);
  const int ee = (int)((long)(wvid + 1) * E / W);

  // n0 = first node with offs2[n] >= eb ; n1 = first node with offs2[n] >= ee
  int lo = 0, hi = N;
  while (lo < hi) { int m = (lo + hi) >> 1; if (offs2[m] >= eb) hi = m; else lo = m + 1; }
  const int n0 = lo;
  lo = 0; hi = N;
  while (lo < hi) { int m = (lo + hi) >> 1; if (offs2[m] >= ee) hi = m; else lo = m + 1; }
  int n1 = lo;
  if (wvid == W - 1) n1 = N;                        // own trailing zero-deg nodes
  if (n0 >= n1) return;

  int p = offs2[n0];
  const int pendall = offs2[n1];
  int n = n0;
  int pe = offs2[n0 + 1];

  float acc0 = 0.f, acc1 = 0.f, acc2 = 0.f, acc3 = 0.f;
  float den0 = 0.f, den1 = 0.f, den2 = 0.f, den3 = 0.f;

  auto flushNode = [&](int node) {
    uint2 w;
    w.x = pk(acc0 / (den0 + 1e-8f), acc1 / (den1 + 1e-8f));
    w.y = pk(acc2 / (den2 + 1e-8f), acc3 / (den3 + 1e-8f));
    *(uint2*)(agg + (size_t)node * 256 + c * 4) = w;
    acc0 = acc1 = acc2 = acc3 = 0.f;
    den0 = den1 = den2 = den3 = 0.f;
  };
  // flush every node whose edge range ends at position q (handles zero-deg chains)
  auto advance = [&](int q) {
    while (pe == q) {
      flushNode(n);
      ++n;
      if (n >= n1) { pe = -1; break; }
      pe = offs2[n + 1];
    }
  };

  float  gA[4], gB[4], gC[4];
  float4 eA[4], eB[4], eC[4];
  auto loadGroup = [&](int base, float* gg, float4* ee_) {
    #pragma unroll
    for (int j = 0; j < 4; ++j) {
      int q = base + j < pendall ? base + j : pendall - 1;   // clamp (safe dup)
      int s = csr_src[q];                                    // uniform s_load
      ee_[j] = csr_es[q];                                    // uniform s_load
      gg[j] = bf2f(h16[(size_t)s * 64 + c]);                 // 128B gather
    }
  };

  advance(p);                                       // leading zero-deg nodes
  if (p < pendall) { loadGroup(p, gA, eA); loadGroup(p + 4, gB, eB); }

  while (p < pendall) {
    loadGroup(p + 8, gC, eC);                       // depth-2 prefetch
    #pragma unroll
    for (int j = 0; j < 4; ++j) {
      if (p + j >= pendall) break;                  // uniform
      den0 += eA[j].x; den1 += eA[j].y; den2 += eA[j].z; den3 += eA[j].w;
      acc0 = fmaf(eA[j].x, gA[j], acc0);
      acc1 = fmaf(eA[j].y, gA[j], acc1);
      acc2 = fmaf(eA[j].z, gA[j], acc2);
      acc3 = fmaf(eA[j].w, gA[j], acc3);
      advance(p + j + 1);                           // uniform node boundary
    }
    p += 4;
    #pragma unroll
    for (int j = 0; j < 4; ++j) { gA[j] = gB[j]; eA[j] = eB[j];
                                  gB[j] = gC[j]; eB[j] = eC[j]; }
  }
}

// ------- pack Pw (256x64 fp32) into bf16 MFMA B-fragment order ------------
__global__ __launch_bounds__(256) void k_pw(const float* __restrict__ Pw,
    unsigned short* __restrict__ Bf)
{
  int i = blockIdx.x * 256 + threadIdx.x;   // 0..16383
  int j    = i & 7;
  int lane = (i >> 3) & 63;
  int cb   = (i >> 9) & 3;
  int ks   = i >> 11;
  int k    = ks * 32 + (lane >> 4) * 8 + j;
  int colg = cb * 16 + (lane & 15);
  Bf[i] = f2bf(Pw[(size_t)k * 64 + colg]);
}

// ------- proj GEMM via MFMA + fused residual/LN/ReLU epilogue -------------
__global__ __launch_bounds__(256) void k_projm(const unsigned short* __restrict__ agg,
    const unsigned short* __restrict__ Bf, const float* __restrict__ x,
    const float* __restrict__ Pb,
    const float* __restrict__ lg, const float* __restrict__ lb,
    float* __restrict__ out, int N)
{
  const int lane = threadIdx.x & 63;
  const int wv = threadIdx.x >> 6;
  const int nt = blockIdx.x * 4 + wv;           // 16-node tile index
  if (nt * 16 >= N) return;
  const int col  = lane & 15;
  const int quad = lane >> 4;
  const int base = nt * 16;

  int na = base + col; if (na >= N) na = N - 1;
  const unsigned short* aptr = agg + (size_t)na * 256 + quad * 8;

  f32x4 acc0 = {0.f, 0.f, 0.f, 0.f};
  f32x4 acc1 = {0.f, 0.f, 0.f, 0.f};
  f32x4 acc2 = {0.f, 0.f, 0.f, 0.f};
  f32x4 acc3 = {0.f, 0.f, 0.f, 0.f};

  #pragma unroll
  for (int ks = 0; ks < 8; ++ks) {
    bf16x8 av = *(const bf16x8*)(aptr + ks * 32);
    bf16x8 b0 = *(const bf16x8*)(Bf + ((size_t)(ks * 4 + 0) * 64 + lane) * 8);
    bf16x8 b1 = *(const bf16x8*)(Bf + ((size_t)(ks * 4 + 1) * 64 + lane) * 8);
    bf16x8 b2 = *(const bf16x8*)(Bf + ((size_t)(ks * 4 + 2) * 64 + lane) * 8);
    bf16x8 b3 = *(const bf16x8*)(Bf + ((size_t)(ks * 4 + 3) * 64 + lane) * 8);
    acc0 = __builtin_amdgcn_mfma_f32_16x16x32_bf16(av, b0, acc0, 0, 0, 0);
    acc1 = __builtin_amdgcn_mfma_f32_16x16x32_bf16(av, b1, acc1, 0, 0, 0);
    acc2 = __builtin_amdgcn_mfma_f32_16x16x32_bf16(av, b2, acc2, 0, 0, 0);
    acc3 = __builtin_amdgcn_mfma_f32_16x16x32_bf16(av, b3, acc3, 0, 0, 0);
  }

  const float pb0 = Pb[col], pb1 = Pb[16 + col], pb2 = Pb[32 + col], pb3 = Pb[48 + col];
  float v[4][4];                                 // [cb][reg]
  #pragma unroll
  for (int r = 0; r < 4; ++r) {
    int node = base + quad * 4 + r; if (node >= N) node = N - 1;
    const float* xr = x + (size_t)node * 64;
    v[0][r] = acc0[r] + pb0 + xr[col];
    v[1][r] = acc1[r] + pb1 + xr[16 + col];
    v[2][r] = acc2[r] + pb2 + xr[32 + col];
    v[3][r] = acc3[r] + pb3 + xr[48 + col];
  }

  float mu[4], inv[4];
  #pragma unroll
  for (int r = 0; r < 4; ++r) {
    float s = (v[0][r] + v[1][r]) + (v[2][r] + v[3][r]);
    s += __shfl_xor(s, 1, 64); s += __shfl_xor(s, 2, 64);
    s += __shfl_xor(s, 4, 64); s += __shfl_xor(s, 8, 64);
    mu[r] = s * 0.015625f;
  }
  #pragma unroll
  for (int r = 0; r < 4; ++r) {
    float d0 = v[0][r] - mu[r], d1 = v[1][r] - mu[r];
    float d2 = v[2][r] - mu[r], d3 = v[3][r] - mu[r];
    float s = fmaf(d0, d0, d1 * d1) + fmaf(d2, d2, d3 * d3);
    s += __shfl_xor(s, 1, 64); s += __shfl_xor(s, 2, 64);
    s += __shfl_xor(s, 4, 64); s += __shfl_xor(s, 8, 64);
    inv[r] = rsqrtf(s * 0.015625f + 1e-5f);
  }

  const float lg0 = lg[col], lg1 = lg[16 + col], lg2 = lg[32 + col], lg3 = lg[48 + col];
  const float lb0 = lb[col], lb1 = lb[16 + col], lb2 = lb[32 + col], lb3 = lb[48 + col];
  #pragma unroll
  for (int r = 0; r < 4; ++r) {
    int node = base + quad * 4 + r;
    if (node < N) {
      float* orow = out + (size_t)node * 64;
      orow[col]      = fmaxf(fmaf(lg0 * (v[0][r] - mu[r]), inv[r], lb0), 0.f);
      orow[16 + col] = fmaxf(fmaf(lg1 * (v[1][r] - mu[r]), inv[r], lb1), 0.f);
      orow[32 + col] = fmaxf(fmaf(lg2 * (v[2][r] - mu[r]), inv[r], lb2), 0.f);
      orow[48 + col] = fmaxf(fmaf(lg3 * (v[3][r] - mu[r]), inv[r], lb3), 0.f);
    }
  }
}

// ---------------------------------------------------------------------------
extern "C" void kernel_launch(void* const* d_in, const int* in_sizes, int n_in,
                              void* d_out, int out_size, void* d_ws, size_t ws_size,
                              hipStream_t stream)
{
  const float* x  = (const float*)d_in[0];
  const int*   ei = (const int*)d_in[1];
  const float* et = (const float*)d_in[2];
  const int*   ct = (const int*)d_in[3];
  const float* Ww = (const float*)d_in[4];
  const float* Wb = (const float*)d_in[5];
  const float* aw = (const float*)d_in[6];
  const float* ab = (const float*)d_in[7];
  const float* dr = (const float*)d_in[8];
  const float* Pw = (const float*)d_in[9];
  const float* Pb = (const float*)d_in[10];
  const float* lg = (const float*)d_in[11];
  const float* lb = (const float*)d_in[12];
  float* out = (float*)d_out;

  const int N = in_sizes[0] / 64;
  const int E = in_sizes[2];

  char* ws = (char*)d_ws;
  size_t off = 0;
  auto take = [&](size_t bytes) -> char* {
    char* p = ws + off;
    off = (off + bytes + 255) & ~(size_t)255;
    return p;
  };
  unsigned short* h16 = (unsigned short*)take((size_t)N * 64 * 2);
  int*    deg    = (int*)take((size_t)N * 4);
  int*    offs   = (int*)take((size_t)N * 4);
  int*    offs2  = (int*)take((size_t)(N + 1) * 4);
  int*    bsums  = (int*)take(512 * 4);
  int*    rank   = (int*)take((size_t)E * 4);
  int*    csr_src= (int*)take((size_t)E * 4);
  float4* csr_es = (float4*)take((size_t)E * 16);
  unsigned short* agg = (unsigned short*)take((size_t)N * 256 * 2);
  float4* u      = (float4*)take((size_t)N * 16);
  float4* v      = (float4*)take((size_t)N * 16);
  unsigned short* Bf = (unsigned short*)take(16384 * 2);

  hipMemsetAsync(deg, 0, (size_t)N * 4, stream);

  k_pw<<<64, 256, 0, stream>>>(Pw, Bf);
  k_hn<<<(N + 63) / 64, 64, 0, stream>>>(x, Ww, Wb, aw, h16, u, v, N);
  k_deg<<<(E + 255) / 256, 256, 0, stream>>>(ei, deg, rank, E);
  const int NB = (N + 255) / 256;
  scan1<<<NB, 256, 0, stream>>>(deg, offs, bsums, N);
  scan2<<<1, 512, 0, stream>>>(bsums, NB);
  scan3<<<NB + 1, 256, 0, stream>>>(offs, bsums, offs2, N, E);
  k_fill<<<(E + 255) / 256, 256, 0, stream>>>(ei, et, ct, dr, u, v, ab,
                                              offs2, rank, csr_src, csr_es, E);
  const int W = 2048 * 4;
  k_agg<<<2048, 256, 0, stream>>>(h16, csr_src, csr_es, offs2, agg, N, E, W);
  const int NT = (N + 15) / 16;
  k_projm<<<(NT + 3) / 4, 256, 0, stream>>>(agg, Bf, x, Pb, lg, lb, out, N);
}

// Round 9
// 248.605 us; speedup vs baseline: 1.2984x; 1.2859x over previous
//
#include <hip/hip_runtime.h>

// ---------------------------------------------------------------------------
// TemporalHeteroConv on MI355X.  N=100000 nodes, E=800000 edges, C=64, H=4.
// Pipeline (r9 = r6 structure; r7 LDS-fusion and r8 streaming k_agg both
// regressed and are reverted):
//   k_init   : zero deg + pack Pw into bf16 MFMA B-fragment order (one disp).
//   k_hd     : FUSED k_hn + k_deg via block-range split. Node blocks: lane =
//              node, h row in registers via scalar-broadcast W, writes h16
//              (bf16) + u/v tables. Edge blocks: rank[e]=atomicAdd(deg[dst]).
//   scan1/2  : exclusive scan of deg (bsums[i>>8] folded into consumers).
//   k_fill   : recomputes scores from u/v (L2-resident), packs ONE 16B CSR
//              record {src, bf16x4 es} per edge -> single random line/edge
//              [r6 wrote 4B+16B to two arrays = 2 lines/edge].
//   k_agg    : wave/node (r6 winner), groups-of-4 prefetch, bf16 h gather;
//              es unpack from records is scalar ALU (wave-uniform).
//   k_projm  : MFMA proj GEMM agg(N,256)@Pw(256,64), wave per 16-node tile,
//              LN+residual+ReLU epilogue in C/D layout.
// ---------------------------------------------------------------------------

typedef __attribute__((ext_vector_type(8))) short bf16x8;
typedef __attribute__((ext_vector_type(4))) float f32x4;

__device__ __forceinline__ unsigned short f2bf(float f) {
  unsigned int u = __float_as_uint(f);
  u += 0x7FFFu + ((u >> 16) & 1u);          // RNE
  return (unsigned short)(u >> 16);
}
__device__ __forceinline__ float bf2f(unsigned short s) {
  return __uint_as_float(((unsigned int)s) << 16);
}
__device__ __forceinline__ unsigned int pk(float a, float b) {
  return (unsigned int)f2bf(a) | ((unsigned int)f2bf(b) << 16);
}
__device__ __forceinline__ float bflo(int u) {
  return __uint_as_float(((unsigned int)u) << 16);
}
__device__ __forceinline__ float bfhi(int u) {
  return __uint_as_float(((unsigned int)u) & 0xFFFF0000u);
}

#define FMA4(P, S, R) { P.x = fmaf(S, R.x, P.x); P.y = fmaf(S, R.y, P.y); \
                        P.z = fmaf(S, R.z, P.z); P.w = fmaf(S, R.w, P.w); }

// ------- init: zero deg + pack Pw into bf16 B-fragment order ---------------
__global__ __launch_bounds__(256) void k_init(const float* __restrict__ Pw,
    unsigned short* __restrict__ Bf, int* __restrict__ deg, int N)
{
  int i = blockIdx.x * 256 + threadIdx.x;
  if (i < N) deg[i] = 0;
  if (i < 16384) {
    int j    = i & 7;
    int lane = (i >> 3) & 63;
    int cb   = (i >> 9) & 3;
    int ks   = i >> 11;
    int k    = ks * 32 + (lane >> 4) * 8 + j;
    int colg = cb * 16 + (lane & 15);
    Bf[i] = f2bf(Pw[(size_t)k * 64 + colg]);
  }
}

// ------- fused h/u/v producer (node blocks) + deg/rank (edge blocks) -------
__global__ __launch_bounds__(256) void k_hd(const float* __restrict__ x,
    const float* __restrict__ Ww, const float* __restrict__ Wb,
    const float* __restrict__ attn_w, const int* __restrict__ ei,
    unsigned short* __restrict__ h16, float4* __restrict__ u,
    float4* __restrict__ v, int* __restrict__ deg, int* __restrict__ rank,
    int N, int E, int NBn)
{
  if ((int)blockIdx.x >= NBn) {               // ---- edge blocks: deg/rank ----
    int e = (blockIdx.x - NBn) * 256 + threadIdx.x;
    if (e < E) rank[e] = atomicAdd(&deg[ei[E + e]], 1);
    return;
  }
  // ---- node blocks: lane = node ----
  const int n = blockIdx.x * 256 + threadIdx.x;
  const bool valid = (n < N);
  const int nc = valid ? n : (N - 1);

  float o[64];
  #pragma unroll
  for (int c = 0; c < 64; ++c) o[c] = Wb[c];

  const float* xr = x + (size_t)nc * 64;
  for (int ch = 0; ch < 16; ++ch) {
    float4 xv = *(const float4*)(xr + ch * 4);
    float a[4] = {xv.x, xv.y, xv.z, xv.w};
    #pragma unroll
    for (int kk = 0; kk < 4; ++kk) {
      const float* Wr = Ww + (size_t)(ch * 4 + kk) * 64;
      #pragma unroll
      for (int c = 0; c < 64; ++c)
        o[c] = fmaf(a[kk], Wr[c], o[c]);
    }
  }

  float4 uu = make_float4(0.f, 0.f, 0.f, 0.f);
  float4 vv = make_float4(0.f, 0.f, 0.f, 0.f);
  const float4* aw = (const float4*)attn_w;
  #pragma unroll
  for (int c = 0; c < 64; ++c) {
    float4 r1 = aw[c];
    float4 r2 = aw[64 + c];
    FMA4(uu, o[c], r1);
    FMA4(vv, o[c], r2);
  }

  if (valid) {
    unsigned int* hr = (unsigned int*)(h16 + (size_t)n * 64);
    #pragma unroll
    for (int i = 0; i < 8; ++i) {
      uint4 w;
      w.x = pk(o[i*8+0], o[i*8+1]);
      w.y = pk(o[i*8+2], o[i*8+3]);
      w.z = pk(o[i*8+4], o[i*8+5]);
      w.w = pk(o[i*8+6], o[i*8+7]);
      *(uint4*)(hr + i * 4) = w;
    }
    u[n] = uu;
    v[n] = vv;
  }
}

// ---------------- CSR offsets: block-local scan + block sums ---------------
__global__ __launch_bounds__(256) void scan1(const int* __restrict__ deg,
    int* __restrict__ offs, int* __restrict__ bsums, int N)
{
  int i = blockIdx.x * 256 + threadIdx.x;
  int lane = threadIdx.x & 63;
  int w = threadIdx.x >> 6;
  int v = (i < N) ? deg[i] : 0;
  int s = v;
  #pragma unroll
  for (int d = 1; d < 64; d <<= 1) {
    int t = __shfl_up(s, d, 64);
    if (lane >= d) s += t;
  }
  __shared__ int wsum[4];
  if (lane == 63) wsum[w] = s;
  __syncthreads();
  int add = 0;
  if (w > 0) add += wsum[0];
  if (w > 1) add += wsum[1];
  if (w > 2) add += wsum[2];
  if (i < N) offs[i] = s - v + add;                 // block-exclusive
  if (threadIdx.x == 255) bsums[blockIdx.x] = wsum[0] + wsum[1] + wsum[2] + wsum[3];
}

__global__ __launch_bounds__(512) void scan2(int* bsums, int NB)
{
  __shared__ int lds[512];
  int t = threadIdx.x;
  int v = (t < NB) ? bsums[t] : 0;
  lds[t] = v;
  __syncthreads();
  for (int s = 1; s < 512; s <<= 1) {
    int a = (t >= s) ? lds[t - s] : 0;
    __syncthreads();
    lds[t] += a;
    __syncthreads();
  }
  if (t < NB) bsums[t] = lds[t] - v;                // exclusive
}

// -------- CSR fill: compute score, pack ONE 16B record per edge ------------
__global__ __launch_bounds__(256) void k_fill(const int* __restrict__ ei,
    const float* __restrict__ et, const int* __restrict__ ctime,
    const float* __restrict__ drate, const float4* __restrict__ u,
    const float4* __restrict__ v, const float* __restrict__ attn_b,
    const int* __restrict__ offs, const int* __restrict__ bsums,
    const int* __restrict__ rank, int4* __restrict__ csr, int E)
{
  int e = blockIdx.x * 256 + threadIdx.x;
  if (e >= E) return;
  const int s = ei[e];
  const int d = ei[E + e];
  const float4 us = u[s];
  const float4 vd = v[d];
  const float4 ab = *(const float4*)attn_b;
  const float lam = log1pf(__expf(drate[0]));
  const float w = __expf(-lam * ((float)ctime[0] - et[e]));

  float4 o; float t;
  t = us.x + vd.x + ab.x; t = (t > 0.f ? t : 0.2f * t) * w; o.x = __expf(t);
  t = us.y + vd.y + ab.y; t = (t > 0.f ? t : 0.2f * t) * w; o.y = __expf(t);
  t = us.z + vd.z + ab.z; t = (t > 0.f ? t : 0.2f * t) * w; o.z = __expf(t);
  t = us.w + vd.w + ab.w; t = (t > 0.f ? t : 0.2f * t) * w; o.w = __expf(t);

  int4 rec;
  rec.x = s;
  rec.y = (int)pk(o.x, o.y);
  rec.z = (int)pk(o.z, o.w);
  rec.w = 0;
  csr[offs[d] + bsums[d >> 8] + rank[e]] = rec;     // single 16B scatter
}

// -------- aggregation: wave/node, pipelined 4-edge groups (r6 winner) ------
__global__ __launch_bounds__(256) void k_agg(const unsigned short* __restrict__ h16,
    const int4* __restrict__ csr, const int* __restrict__ offs,
    const int* __restrict__ bsums, unsigned short* __restrict__ agg,
    int N, int E)
{
  const int c = threadIdx.x & 63;
  const int wid = blockIdx.x * 4 + (threadIdx.x >> 6);
  const int wstride = gridDim.x * 4;

  for (int n0 = wid; n0 < N; n0 += wstride) {
    const int n = __builtin_amdgcn_readfirstlane(n0);
    const int p0 = offs[n] + bsums[n >> 8];
    const int p1 = (n + 1 < N) ? (offs[n + 1] + bsums[(n + 1) >> 8]) : E;
    const int nf = (p1 - p0) & ~3;                  // full-group edge count

    float acc0 = 0.f, acc1 = 0.f, acc2 = 0.f, acc3 = 0.f;
    float den0 = 0.f, den1 = 0.f, den2 = 0.f, den3 = 0.f;

    int4 rA0, rA1, rA2, rA3;                        // records: uniform s_loads
    float gA0 = 0.f, gA1 = 0.f, gA2 = 0.f, gA3 = 0.f;
    if (nf) {
      rA0 = csr[p0];     rA1 = csr[p0 + 1];
      rA2 = csr[p0 + 2]; rA3 = csr[p0 + 3];
      gA0 = bf2f(h16[(size_t)rA0.x * 64 + c]);
      gA1 = bf2f(h16[(size_t)rA1.x * 64 + c]);
      gA2 = bf2f(h16[(size_t)rA2.x * 64 + c]);
      gA3 = bf2f(h16[(size_t)rA3.x * 64 + c]);
    }
    for (int p = p0; p < p0 + nf; p += 4) {
      int4 rB0, rB1, rB2, rB3;
      float gB0, gB1, gB2, gB3;
      const bool more = (p + 4 < p0 + nf);
      if (more) {                                   // prefetch next group
        rB0 = csr[p + 4]; rB1 = csr[p + 5];
        rB2 = csr[p + 6]; rB3 = csr[p + 7];
        gB0 = bf2f(h16[(size_t)rB0.x * 64 + c]);
        gB1 = bf2f(h16[(size_t)rB1.x * 64 + c]);
        gB2 = bf2f(h16[(size_t)rB2.x * 64 + c]);
        gB3 = bf2f(h16[(size_t)rB3.x * 64 + c]);
      }
      // scalar unpack of bf16 es (wave-uniform)
      float e00 = bflo(rA0.y), e01 = bfhi(rA0.y), e02 = bflo(rA0.z), e03 = bfhi(rA0.z);
      float e10 = bflo(rA1.y), e11 = bfhi(rA1.y), e12 = bflo(rA1.z), e13 = bfhi(rA1.z);
      float e20 = bflo(rA2.y), e21 = bfhi(rA2.y), e22 = bflo(rA2.z), e23 = bfhi(rA2.z);
      float e30 = bflo(rA3.y), e31 = bfhi(rA3.y), e32 = bflo(rA3.z), e33 = bfhi(rA3.z);
      den0 += (e00 + e10) + (e20 + e30);
      den1 += (e01 + e11) + (e21 + e31);
      den2 += (e02 + e12) + (e22 + e32);
      den3 += (e03 + e13) + (e23 + e33);
      acc0 = fmaf(e00, gA0, fmaf(e10, gA1, fmaf(e20, gA2, fmaf(e30, gA3, acc0))));
      acc1 = fmaf(e01, gA0, fmaf(e11, gA1, fmaf(e21, gA2, fmaf(e31, gA3, acc1))));
      acc2 = fmaf(e02, gA0, fmaf(e12, gA1, fmaf(e22, gA2, fmaf(e32, gA3, acc2))));
      acc3 = fmaf(e03, gA0, fmaf(e13, gA1, fmaf(e23, gA2, fmaf(e33, gA3, acc3))));
      if (more) {
        rA0 = rB0; rA1 = rB1; rA2 = rB2; rA3 = rB3;
        gA0 = gB0; gA1 = gB1; gA2 = gB2; gA3 = gB3;
      }
    }
    for (int p = p0 + nf; p < p1; ++p) {            // tail (<=3, wave-uniform)
      int4 r = csr[p];
      float g = bf2f(h16[(size_t)r.x * 64 + c]);
      float e0 = bflo(r.y), e1 = bfhi(r.y), e2 = bflo(r.z), e3 = bfhi(r.z);
      den0 += e0; den1 += e1; den2 += e2; den3 += e3;
      acc0 = fmaf(e0, g, acc0);
      acc1 = fmaf(e1, g, acc1);
      acc2 = fmaf(e2, g, acc2);
      acc3 = fmaf(e3, g, acc3);
    }
    uint2 w;
    w.x = pk(acc0 / (den0 + 1e-8f), acc1 / (den1 + 1e-8f));
    w.y = pk(acc2 / (den2 + 1e-8f), acc3 / (den3 + 1e-8f));
    *(uint2*)(agg + (size_t)n * 256 + c * 4) = w;   // coalesced b64
  }
}

// ------- proj GEMM via MFMA + fused residual/LN/ReLU epilogue -------------
__global__ __launch_bounds__(256) void k_projm(const unsigned short* __restrict__ agg,
    const unsigned short* __restrict__ Bf, const float* __restrict__ x,
    const float* __restrict__ Pb,
    const float* __restrict__ lg, const float* __restrict__ lb,
    float* __restrict__ out, int N)
{
  const int lane = threadIdx.x & 63;
  const int wv = threadIdx.x >> 6;
  const int nt = blockIdx.x * 4 + wv;           // 16-node tile index
  if (nt * 16 >= N) return;
  const int col  = lane & 15;
  const int quad = lane >> 4;
  const int base = nt * 16;

  int na = base + col; if (na >= N) na = N - 1;
  const unsigned short* aptr = agg + (size_t)na * 256 + quad * 8;

  f32x4 acc0 = {0.f, 0.f, 0.f, 0.f};
  f32x4 acc1 = {0.f, 0.f, 0.f, 0.f};
  f32x4 acc2 = {0.f, 0.f, 0.f, 0.f};
  f32x4 acc3 = {0.f, 0.f, 0.f, 0.f};

  #pragma unroll
  for (int ks = 0; ks < 8; ++ks) {
    bf16x8 av = *(const bf16x8*)(aptr + ks * 32);
    bf16x8 b0 = *(const bf16x8*)(Bf + ((size_t)(ks * 4 + 0) * 64 + lane) * 8);
    bf16x8 b1 = *(const bf16x8*)(Bf + ((size_t)(ks * 4 + 1) * 64 + lane) * 8);
    bf16x8 b2 = *(const bf16x8*)(Bf + ((size_t)(ks * 4 + 2) * 64 + lane) * 8);
    bf16x8 b3 = *(const bf16x8*)(Bf + ((size_t)(ks * 4 + 3) * 64 + lane) * 8);
    acc0 = __builtin_amdgcn_mfma_f32_16x16x32_bf16(av, b0, acc0, 0, 0, 0);
    acc1 = __builtin_amdgcn_mfma_f32_16x16x32_bf16(av, b1, acc1, 0, 0, 0);
    acc2 = __builtin_amdgcn_mfma_f32_16x16x32_bf16(av, b2, acc2, 0, 0, 0);
    acc3 = __builtin_amdgcn_mfma_f32_16x16x32_bf16(av, b3, acc3, 0, 0, 0);
  }

  const float pb0 = Pb[col], pb1 = Pb[16 + col], pb2 = Pb[32 + col], pb3 = Pb[48 + col];
  float v[4][4];                                 // [cb][reg]
  #pragma unroll
  for (int r = 0; r < 4; ++r) {
    int node = base + quad * 4 + r; if (node >= N) node = N - 1;
    const float* xr = x + (size_t)node * 64;
    v[0][r] = acc0[r] + pb0 + xr[col];
    v[1][r] = acc1[r] + pb1 + xr[16 + col];
    v[2][r] = acc2[r] + pb2 + xr[32 + col];
    v[3][r] = acc3[r] + pb3 + xr[48 + col];
  }

  float mu[4], inv[4];
  #pragma unroll
  for (int r = 0; r < 4; ++r) {
    float s = (v[0][r] + v[1][r]) + (v[2][r] + v[3][r]);
    s += __shfl_xor(s, 1, 64); s += __shfl_xor(s, 2, 64);
    s += __shfl_xor(s, 4, 64); s += __shfl_xor(s, 8, 64);
    mu[r] = s * 0.015625f;
  }
  #pragma unroll
  for (int r = 0; r < 4; ++r) {
    float d0 = v[0][r] - mu[r], d1 = v[1][r] - mu[r];
    float d2 = v[2][r] - mu[r], d3 = v[3][r] - mu[r];
    float s = fmaf(d0, d0, d1 * d1) + fmaf(d2, d2, d3 * d3);
    s += __shfl_xor(s, 1, 64); s += __shfl_xor(s, 2, 64);
    s += __shfl_xor(s, 4, 64); s += __shfl_xor(s, 8, 64);
    inv[r] = rsqrtf(s * 0.015625f + 1e-5f);
  }

  const float lg0 = lg[col], lg1 = lg[16 + col], lg2 = lg[32 + col], lg3 = lg[48 + col];
  const float lb0 = lb[col], lb1 = lb[16 + col], lb2 = lb[32 + col], lb3 = lb[48 + col];
  #pragma unroll
  for (int r = 0; r < 4; ++r) {
    int node = base + quad * 4 + r;
    if (node < N) {
      float* orow = out + (size_t)node * 64;
      orow[col]      = fmaxf(fmaf(lg0 * (v[0][r] - mu[r]), inv[r], lb0), 0.f);
      orow[16 + col] = fmaxf(fmaf(lg1 * (v[1][r] - mu[r]), inv[r], lb1), 0.f);
      orow[32 + col] = fmaxf(fmaf(lg2 * (v[2][r] - mu[r]), inv[r], lb2), 0.f);
      orow[48 + col] = fmaxf(fmaf(lg3 * (v[3][r] - mu[r]), inv[r], lb3), 0.f);
    }
  }
}

// ---------------------------------------------------------------------------
extern "C" void kernel_launch(void* const* d_in, const int* in_sizes, int n_in,
                              void* d_out, int out_size, void* d_ws, size_t ws_size,
                              hipStream_t stream)
{
  const float* x  = (const float*)d_in[0];
  const int*   ei = (const int*)d_in[1];
  const float* et = (const float*)d_in[2];
  const int*   ct = (const int*)d_in[3];
  const float* Ww = (const float*)d_in[4];
  const float* Wb = (const float*)d_in[5];
  const float* aw = (const float*)d_in[6];
  const float* ab = (const float*)d_in[7];
  const float* dr = (const float*)d_in[8];
  const float* Pw = (const float*)d_in[9];
  const float* Pb = (const float*)d_in[10];
  const float* lg = (const float*)d_in[11];
  const float* lb = (const float*)d_in[12];
  float* out = (float*)d_out;

  const int N = in_sizes[0] / 64;
  const int E = in_sizes[2];

  char* ws = (char*)d_ws;
  size_t off = 0;
  auto take = [&](size_t bytes) -> char* {
    char* p = ws + off;
    off = (off + bytes + 255) & ~(size_t)255;
    return p;
  };
  unsigned short* h16 = (unsigned short*)take((size_t)N * 64 * 2);
  int*    deg    = (int*)take((size_t)N * 4);
  int*    offs   = (int*)take((size_t)N * 4);
  int*    bsums  = (int*)take(512 * 4);
  int*    rank   = (int*)take((size_t)E * 4);
  int4*   csr    = (int4*)take((size_t)E * 16);
  unsigned short* agg = (unsigned short*)take((size_t)N * 256 * 2);
  float4* u      = (float4*)take((size_t)N * 16);
  float4* v      = (float4*)take((size_t)N * 16);
  unsigned short* Bf = (unsigned short*)take(16384 * 2);

  const int NBn = (N + 255) / 256;
  const int NBe = (E + 255) / 256;

  k_init<<<NBn, 256, 0, stream>>>(Pw, Bf, deg, N);
  k_hd<<<NBn + NBe, 256, 0, stream>>>(x, Ww, Wb, aw, ei, h16, u, v, deg, rank, N, E, NBn);
  scan1<<<NBn, 256, 0, stream>>>(deg, offs, bsums, N);
  scan2<<<1, 512, 0, stream>>>(bsums, NBn);
  k_fill<<<NBe, 256, 0, stream>>>(ei, et, ct, dr, u, v, ab, offs, bsums, rank, csr, E);
  k_agg<<<2048, 256, 0, stream>>>(h16, csr, offs, bsums, agg, N, E);
  const int NT = (N + 15) / 16;
  k_projm<<<(NT + 3) / 4, 256, 0, stream>>>(agg, Bf, x, Pb, lg, lb, out, N);
}